// Round 1
// baseline (337.522 us; speedup 1.0000x reference)
//
#include <hip/hip_runtime.h>

// LabelGenerator: masks [32,1,768,768] f32 in {0,1}
//  out0 = 35x35 box mean (SAME, zero pad)               -> f32 [32,768,768]
//  out1 = pfm: mask?1 : (31x31 dilation?0 : 2)          -> written as f32 0/1/2
// Dilation on a 0/1 mask == (31x31 box sum >= 1), so both outputs are
// separable sliding-window sums computed from one LDS-staged halo tile.

#define BATCH 32
#define HH 768
#define WW 768
#define NPIX (HH * WW)

constexpr int TX = 64;          // output tile width
constexpr int TY = 32;          // output tile height
constexpr int HALO = 17;        // 35//2 (covers 31//2=15 too)
constexpr int IW = TX + 2 * HALO;   // 98
constexpr int IH = TY + 2 * HALO;   // 66
constexpr int SIN = IW + 1;         // 99: odd stride -> <=2-way LDS conflicts (free)

__global__ __launch_bounds__(256)
void label_gen_kernel(const float* __restrict__ in, float* __restrict__ out) {
    __shared__ float s_in[IH * SIN];    // halo input tile
    __shared__ float s_v35[TY * SIN];   // vertical 35-window sums
    __shared__ float s_v31[TY * SIN];   // vertical 31-window sums

    const int tid = threadIdx.x;
    const int gx0 = blockIdx.x * TX;
    const int gy0 = blockIdx.y * TY;
    const int b   = blockIdx.z;
    const float* __restrict__ src = in + (size_t)b * NPIX;

    // ---- phase 1: global -> LDS halo tile (zero pad OOB) ----
    for (int idx = tid; idx < IH * IW; idx += 256) {
        int r = idx / IW;
        int c = idx - r * IW;
        int gy = gy0 - HALO + r;
        int gx = gx0 - HALO + c;
        float v = 0.0f;
        if (gy >= 0 && gy < HH && gx >= 0 && gx < WW) v = src[gy * WW + gx];
        s_in[r * SIN + c] = v;
    }
    __syncthreads();

    // ---- phase 2: vertical sliding sums. 196 threads = 2 y-segments x 98 cols ----
    if (tid < 196) {
        const int seg = (tid >= 98) ? 1 : 0;
        const int c   = tid - seg * 98;
        const int y0  = seg * (TY / 2);
        float s35 = 0.0f;
        #pragma unroll
        for (int r = 0; r < 35; ++r) s35 += s_in[(y0 + r) * SIN + c];
        float s31 = s35 - s_in[(y0 + 0) * SIN + c] - s_in[(y0 + 1) * SIN + c]
                        - s_in[(y0 + 33) * SIN + c] - s_in[(y0 + 34) * SIN + c];
        s_v35[y0 * SIN + c] = s35;
        s_v31[y0 * SIN + c] = s31;
        for (int y = y0 + 1; y < y0 + TY / 2; ++y) {
            s35 += s_in[(y + 34) * SIN + c] - s_in[(y - 1) * SIN + c];
            s31 += s_in[(y + 32) * SIN + c] - s_in[(y + 1) * SIN + c];
            s_v35[y * SIN + c] = s35;
            s_v31[y * SIN + c] = s31;
        }
    }
    __syncthreads();

    // ---- phase 3: horizontal sliding sums + outputs. 256 threads = 32 rows x 8 segs ----
    const int y  = tid >> 3;          // 0..31
    const int x0 = (tid & 7) * 8;     // 8 consecutive x per thread
    float h35 = 0.0f, h31 = 0.0f;
    #pragma unroll
    for (int c = x0; c < x0 + 35; ++c)      h35 += s_v35[y * SIN + c];
    #pragma unroll
    for (int c = x0 + 2; c <= x0 + 32; ++c) h31 += s_v31[y * SIN + c];

    float* __restrict__ out_r = out + (size_t)b * NPIX + (size_t)(gy0 + y) * WW + gx0;
    float* __restrict__ out_p = out + (size_t)BATCH * NPIX + (size_t)b * NPIX
                                    + (size_t)(gy0 + y) * WW + gx0;
    #pragma unroll
    for (int i = 0; i < 8; ++i) {
        const int x = x0 + i;
        const float m = s_in[(y + HALO) * SIN + (x + HALO)];
        out_r[x] = h35 * (1.0f / 1225.0f);
        out_p[x] = (m > 0.5f) ? 1.0f : ((h31 > 0.5f) ? 0.0f : 2.0f);
        if (i < 7) {
            h35 += s_v35[y * SIN + x + 35] - s_v35[y * SIN + x];
            h31 += s_v31[y * SIN + x + 33] - s_v31[y * SIN + x + 2];
        }
    }
}

extern "C" void kernel_launch(void* const* d_in, const int* in_sizes, int n_in,
                              void* d_out, int out_size, void* d_ws, size_t ws_size,
                              hipStream_t stream) {
    const float* masks = (const float*)d_in[0];
    float* out = (float*)d_out;
    dim3 grid(WW / TX, HH / TY, BATCH);   // 12 x 24 x 32 = 9216 blocks
    dim3 block(256);
    label_gen_kernel<<<grid, block, 0, stream>>>(masks, out);
}

// Round 2
// 269.652 us; speedup vs baseline: 1.2517x; 1.2517x over previous
//
#include <hip/hip_runtime.h>

// LabelGenerator: masks [32,1,768,768] f32 in {0,1}
//  out0 = 35x35 box mean (SAME, zero pad)      -> f32 [32,768,768]
//  out1 = pfm: mask?1 : (31x31 dilation?0 : 2) -> f32 values 0/1/2
// Two-pass: vertical sliding sums (register streaming, packed u16 to ws),
// then horizontal sliding sums (LDS tile -> register window, SWAR init).
// Dilation on 0/1 mask == (31x31 box sum >= 1).

#define BATCH 32
#define HH 768
#define WW 768
#define NPIX (HH * WW)

// ---------------- Pass 1: vertical box sums -> packed u16 (v35 | v31<<8) ----
constexpr int P1_CH  = 16;   // rows per block
constexpr int P1_TPB = 192;  // threads; each owns 4 consecutive cols (192*4=768)

__device__ inline float4 ld_row(const float* p, int r) {
    if ((unsigned)r < (unsigned)HH) return *(const float4*)(p + (size_t)r * WW);
    return make_float4(0.f, 0.f, 0.f, 0.f);
}

__global__ __launch_bounds__(P1_TPB)
void vpass_kernel(const float* __restrict__ in, unsigned short* __restrict__ vs) {
    const int c0 = threadIdx.x * 4;
    const int y0 = blockIdx.x * P1_CH;
    const int b  = blockIdx.y;
    const float* __restrict__ src = in + (size_t)b * NPIX + c0;
    unsigned short* __restrict__ dst = vs + (size_t)b * NPIX + c0;

    float v35[4] = {0.f, 0.f, 0.f, 0.f};
    float v31[4] = {0.f, 0.f, 0.f, 0.f};
    // init windows centered at y0: v35 rows [y0-17,y0+17], v31 rows [y0-15,y0+15]
    #pragma unroll
    for (int k = 0; k < 35; ++k) {
        const int r = y0 - 17 + k;
        const float4 a = ld_row(src, r);
        v35[0] += a.x; v35[1] += a.y; v35[2] += a.z; v35[3] += a.w;
        if (k >= 2 && k <= 32) { v31[0] += a.x; v31[1] += a.y; v31[2] += a.z; v31[3] += a.w; }
    }
    for (int y = y0; y < y0 + P1_CH; ++y) {
        ushort4 o;
        o.x = (unsigned short)((int)v35[0] | ((int)v31[0] << 8));
        o.y = (unsigned short)((int)v35[1] | ((int)v31[1] << 8));
        o.z = (unsigned short)((int)v35[2] | ((int)v31[2] << 8));
        o.w = (unsigned short)((int)v35[3] | ((int)v31[3] << 8));
        *(ushort4*)(dst + (size_t)y * WW) = o;
        if (y + 1 < y0 + P1_CH) {
            const float4 a18 = ld_row(src, y + 18);
            const float4 s17 = ld_row(src, y - 17);
            const float4 a16 = ld_row(src, y + 16);
            const float4 s15 = ld_row(src, y - 15);
            v35[0] += a18.x - s17.x; v35[1] += a18.y - s17.y;
            v35[2] += a18.z - s17.z; v35[3] += a18.w - s17.w;
            v31[0] += a16.x - s15.x; v31[1] += a16.y - s15.y;
            v31[2] += a16.z - s15.z; v31[3] += a16.w - s15.w;
        }
    }
}

// ---------------- Pass 2: horizontal sliding sums + outputs -----------------
constexpr int TX2 = 128, TY2 = 32;
constexpr int SW2 = 168;   // LDS row stride in u16 (byte stride 336 = 21*16, 16B-aligned)

__global__ __launch_bounds__(256)
void hpass_kernel(const unsigned short* __restrict__ vs, const float* __restrict__ in,
                  float* __restrict__ out) {
    __shared__ __align__(16) unsigned short s_v[TY2 * SW2];
    const int tid = threadIdx.x;
    const int gx0 = blockIdx.x * TX2, gy0 = blockIdx.y * TY2, b = blockIdx.z;
    const unsigned short* __restrict__ vsb = vs + (size_t)b * NPIX;

    // stage 32 rows x 168 u16 (as 84 u32/row); s_v[c] = V[gx0 - 18 + c]
    for (int idx = tid; idx < TY2 * 84; idx += 256) {
        const int r = idx / 84, c2 = idx - r * 84;
        const int gx = gx0 - 18 + 2 * c2;
        unsigned int v = 0;
        if ((unsigned)gx < (unsigned)WW)
            v = *(const unsigned int*)(vsb + (size_t)(gy0 + r) * WW + gx);
        *(unsigned int*)(&s_v[r * SW2 + 2 * c2]) = v;
    }
    __syncthreads();

    const int y  = tid >> 3;
    const int x0 = (tid & 7) * 16;    // 16 outputs per thread

    // pull 56-u16 window into registers (7x ds_read_b128)
    unsigned int d[28];
    const uint4* rp = (const uint4*)(s_v + y * SW2 + x0);
    #pragma unroll
    for (int k = 0; k < 7; ++k) ((uint4*)d)[k] = rp[k];

    // window for output x=x0+i: h35 sums k=[1+i,35+i], h31 sums k=[3+i,33+i]
    // (k indexes u16s relative to x0; dword j holds k=2j,2j+1)
    auto sum35 = [](unsigned int g) { return (int)((g & 0xffu) + ((g >> 16) & 0xffu)); };
    auto sum31 = [](unsigned int g) { return (int)(((g >> 8) & 0xffu) + (g >> 24)); };
    const unsigned int G1 = d[2] + d[3] + d[4] + d[5] + d[6] + d[7] + d[8];
    const unsigned int G2 = d[9] + d[10] + d[11] + d[12] + d[13] + d[14] + d[15];
    const unsigned int G3 = d[16];
    const unsigned int G4 = d[1] + d[17];
    int h35 = sum35(G1) + sum35(G2) + sum35(G3) + sum35(G4) + (int)((d[0] >> 16) & 0xffu);
    int h31 = sum31(G1) + sum31(G2) + sum31(G3) + (int)(d[1] >> 24);

    auto lo8 = [&](int k) { return (int)((d[k >> 1] >> ((k & 1) * 16)) & 0xffu); };
    auto hi8 = [&](int k) { return (int)((d[k >> 1] >> ((k & 1) * 16 + 8)) & 0xffu); };

    float m[16];
    const float* mrow = in + (size_t)b * NPIX + (size_t)(gy0 + y) * WW + gx0 + x0;
    #pragma unroll
    for (int k = 0; k < 4; ++k) ((float4*)m)[k] = ((const float4*)mrow)[k];

    float r_out[16], p_out[16];
    #pragma unroll
    for (int i = 0; i < 16; ++i) {
        r_out[i] = (float)h35 * (1.0f / 1225.0f);
        p_out[i] = (m[i] > 0.5f) ? 1.0f : ((h31 > 0) ? 0.0f : 2.0f);
        if (i < 15) {
            h35 += lo8(36 + i) - lo8(1 + i);
            h31 += hi8(34 + i) - hi8(3 + i);
        }
    }
    float* orow = out + (size_t)b * NPIX + (size_t)(gy0 + y) * WW + gx0 + x0;
    float* prow = orow + (size_t)BATCH * NPIX;
    #pragma unroll
    for (int k = 0; k < 4; ++k) ((float4*)orow)[k] = ((const float4*)r_out)[k];
    #pragma unroll
    for (int k = 0; k < 4; ++k) ((float4*)prow)[k] = ((const float4*)p_out)[k];
}

// ---------------- Fallback: single-kernel tiled version (R1, passing) -------
constexpr int TX = 64;
constexpr int TY = 32;
constexpr int HALO = 17;
constexpr int IW = TX + 2 * HALO;   // 98
constexpr int IH = TY + 2 * HALO;   // 66
constexpr int SIN = IW + 1;         // 99

__global__ __launch_bounds__(256)
void label_gen_kernel(const float* __restrict__ in, float* __restrict__ out) {
    __shared__ float s_in[IH * SIN];
    __shared__ float s_v35[TY * SIN];
    __shared__ float s_v31[TY * SIN];

    const int tid = threadIdx.x;
    const int gx0 = blockIdx.x * TX;
    const int gy0 = blockIdx.y * TY;
    const int b   = blockIdx.z;
    const float* __restrict__ src = in + (size_t)b * NPIX;

    for (int idx = tid; idx < IH * IW; idx += 256) {
        int r = idx / IW;
        int c = idx - r * IW;
        int gy = gy0 - HALO + r;
        int gx = gx0 - HALO + c;
        float v = 0.0f;
        if (gy >= 0 && gy < HH && gx >= 0 && gx < WW) v = src[gy * WW + gx];
        s_in[r * SIN + c] = v;
    }
    __syncthreads();

    if (tid < 196) {
        const int seg = (tid >= 98) ? 1 : 0;
        const int c   = tid - seg * 98;
        const int y0  = seg * (TY / 2);
        float s35 = 0.0f;
        #pragma unroll
        for (int r = 0; r < 35; ++r) s35 += s_in[(y0 + r) * SIN + c];
        float s31 = s35 - s_in[(y0 + 0) * SIN + c] - s_in[(y0 + 1) * SIN + c]
                        - s_in[(y0 + 33) * SIN + c] - s_in[(y0 + 34) * SIN + c];
        s_v35[y0 * SIN + c] = s35;
        s_v31[y0 * SIN + c] = s31;
        for (int y = y0 + 1; y < y0 + TY / 2; ++y) {
            s35 += s_in[(y + 34) * SIN + c] - s_in[(y - 1) * SIN + c];
            s31 += s_in[(y + 32) * SIN + c] - s_in[(y + 1) * SIN + c];
            s_v35[y * SIN + c] = s35;
            s_v31[y * SIN + c] = s31;
        }
    }
    __syncthreads();

    const int y  = tid >> 3;
    const int x0 = (tid & 7) * 8;
    float h35 = 0.0f, h31 = 0.0f;
    #pragma unroll
    for (int c = x0; c < x0 + 35; ++c)      h35 += s_v35[y * SIN + c];
    #pragma unroll
    for (int c = x0 + 2; c <= x0 + 32; ++c) h31 += s_v31[y * SIN + c];

    float* __restrict__ out_r = out + (size_t)b * NPIX + (size_t)(gy0 + y) * WW + gx0;
    float* __restrict__ out_p = out + (size_t)BATCH * NPIX + (size_t)b * NPIX
                                    + (size_t)(gy0 + y) * WW + gx0;
    #pragma unroll
    for (int i = 0; i < 8; ++i) {
        const int x = x0 + i;
        const float mm = s_in[(y + HALO) * SIN + (x + HALO)];
        out_r[x] = h35 * (1.0f / 1225.0f);
        out_p[x] = (mm > 0.5f) ? 1.0f : ((h31 > 0.5f) ? 0.0f : 2.0f);
        if (i < 7) {
            h35 += s_v35[y * SIN + x + 35] - s_v35[y * SIN + x];
            h31 += s_v31[y * SIN + x + 33] - s_v31[y * SIN + x + 2];
        }
    }
}

extern "C" void kernel_launch(void* const* d_in, const int* in_sizes, int n_in,
                              void* d_out, int out_size, void* d_ws, size_t ws_size,
                              hipStream_t stream) {
    const float* masks = (const float*)d_in[0];
    float* out = (float*)d_out;
    const size_t need = (size_t)BATCH * NPIX * sizeof(unsigned short);  // 37.7 MB
    if (ws_size >= need) {
        unsigned short* vsmap = (unsigned short*)d_ws;
        dim3 g1(HH / P1_CH, BATCH);           // 48 x 32
        vpass_kernel<<<g1, P1_TPB, 0, stream>>>(masks, vsmap);
        dim3 g2(WW / TX2, HH / TY2, BATCH);   // 6 x 24 x 32
        hpass_kernel<<<g2, 256, 0, stream>>>(vsmap, masks, out);
    } else {
        dim3 grid(WW / TX, HH / TY, BATCH);
        label_gen_kernel<<<grid, 256, 0, stream>>>(masks, out);
    }
}

// Round 3
// 268.532 us; speedup vs baseline: 1.2569x; 1.0042x over previous
//
#include <hip/hip_runtime.h>

// LabelGenerator: masks [32,1,768,768] f32 in {0,1}
//  out0 = 35x35 box mean (SAME, zero pad)      -> f32 [32,768,768]
//  out1 = pfm: mask?1 : (31x31 dilation?0 : 2) -> f32 values 0/1/2
// Bit-packed two-pass:
//  Pass 1: per-row ballot -> row bitset -> H35/H31 horizontal window sums via
//          popcount + 1-bit slides; pack H35|H31<<6|mask<<12 into u16 ws map.
//  Pass 2: vertical sliding sums over the u16 map, SWAR 4x16-bit register
//          accumulators, no LDS, coalesced float4 stores.
// Dilation on a 0/1 mask == (31x31 box sum >= 1).

#define BATCH 32
#define HH 768
#define WW 768
#define NPIX (HH * WW)

// ---------------- Pass 1: horizontal ----------------
constexpr int P1_RPW = 8;   // rows per wave; block = 4 waves = 32 rows

__global__ __launch_bounds__(256)
void hpass1_kernel(const float* __restrict__ in, unsigned short* __restrict__ hmap) {
    __shared__ unsigned long long sbits[4][12];
    const int lane = threadIdx.x & 63;
    const int wv   = threadIdx.x >> 6;
    const int b    = blockIdx.y;
    const int row0 = blockIdx.x * (4 * P1_RPW) + wv * P1_RPW;
    const float* __restrict__ src = in + (size_t)b * NPIX;
    unsigned short* __restrict__ dst = hmap + (size_t)b * NPIX;

    for (int k = 0; k < P1_RPW; ++k) {
        const int row = row0 + k;
        const float* rp = src + (size_t)row * WW;
        float v[12];
        #pragma unroll
        for (int j = 0; j < 12; ++j) v[j] = rp[64 * j + lane];
        unsigned long long bb[12];
        #pragma unroll
        for (int j = 0; j < 12; ++j) bb[j] = __ballot(v[j] > 0.5f);
        if (lane == 0) {
            #pragma unroll
            for (int j = 0; j < 12; ++j) sbits[wv][j] = bb[j];
        }
        __builtin_amdgcn_wave_barrier();   // pin LDS write->read order (same wave)
        // 64-bit window starting at column 12*lane - 17
        const int s  = 12 * lane - 17;
        const int i0 = s >> 6;             // arithmetic: -1 for lanes 0..1
        const int sh = s & 63;
        unsigned long long lo = (i0 >= 0) ? sbits[wv][i0] : 0ull;
        unsigned long long hi = (i0 + 1 < 12) ? sbits[wv][i0 + 1] : 0ull;
        unsigned long long win = sh ? ((lo >> sh) | (hi << (64 - sh))) : lo;
        __builtin_amdgcn_wave_barrier();   // reads done before next iter's writes
        // H35 over cols [c-17,c+17], H31 over [c-15,c+15], c = 12*lane
        int h35 = (int)__popcll(win & 0x7FFFFFFFFull);        // bits 0..34
        int h31 = (int)__popcll((win >> 2) & 0x7FFFFFFFull);  // bits 2..32
        unsigned short o[12] __attribute__((aligned(8)));
        #pragma unroll
        for (int i = 0; i < 12; ++i) {
            const int m = (int)((win >> (17 + i)) & 1ull);
            o[i] = (unsigned short)(h35 | (h31 << 6) | (m << 12));
            h35 += (int)((win >> (35 + i)) & 1ull) - (int)((win >> i) & 1ull);
            h31 += (int)((win >> (33 + i)) & 1ull) - (int)((win >> (2 + i)) & 1ull);
        }
        unsigned short* op = dst + (size_t)row * WW + lane * 12;
        ((uint2*)op)[0] = ((const uint2*)o)[0];
        ((uint2*)op)[1] = ((const uint2*)o)[1];
        ((uint2*)op)[2] = ((const uint2*)o)[2];
    }
}

// ---------------- Pass 2: vertical ----------------
constexpr int SH = 48;   // output rows per block; grid (768/48=16, 32)

__device__ inline unsigned long long ldh(const unsigned short* p, int r, int c0) {
    if ((unsigned)r < (unsigned)HH)
        return *(const unsigned long long*)(p + (size_t)r * WW + c0);
    return 0ull;
}

__global__ __launch_bounds__(192)
void vpass2_kernel(const unsigned short* __restrict__ hmap, float* __restrict__ out) {
    const int t  = threadIdx.x;       // 0..191
    const int c0 = 4 * t;             // 4 consecutive cols
    const int y0 = blockIdx.x * SH;
    const int b  = blockIdx.y;
    const unsigned short* __restrict__ hb = hmap + (size_t)b * NPIX;
    const unsigned long long M6 = 0x003F003F003F003Full;

    unsigned long long v35 = 0, v31 = 0;   // SWAR 4x16-bit column sums
    #pragma unroll
    for (int k = 0; k < 35; ++k) {
        const unsigned long long w = ldh(hb, y0 - 17 + k, c0);
        v35 += w & M6;
        if (k >= 2 && k <= 32) v31 += (w >> 6) & M6;
    }

    float* orow = out + (size_t)b * NPIX + (size_t)y0 * WW + c0;
    float* prow = orow + (size_t)BATCH * NPIX;
    for (int y = y0; y < y0 + SH; ++y) {
        const unsigned long long hc =
            *(const unsigned long long*)(hb + (size_t)y * WW + c0);
        // issue slide loads early (ILP)
        const unsigned long long nA = ldh(hb, y + 18, c0);
        const unsigned long long nB = ldh(hb, y + 16, c0);
        const unsigned long long oA = ldh(hb, y - 17, c0);
        const unsigned long long oB = ldh(hb, y - 15, c0);

        float4 r4, p4;
        {
            const int a0 = (int)(v35 & 0xFFFF), a1 = (int)((v35 >> 16) & 0xFFFF);
            const int a2 = (int)((v35 >> 32) & 0xFFFF), a3 = (int)(v35 >> 48);
            r4.x = a0 * (1.0f / 1225.0f); r4.y = a1 * (1.0f / 1225.0f);
            r4.z = a2 * (1.0f / 1225.0f); r4.w = a3 * (1.0f / 1225.0f);
        }
        {
            const int d0 = (int)(v31 & 0xFFFF), d1 = (int)((v31 >> 16) & 0xFFFF);
            const int d2 = (int)((v31 >> 32) & 0xFFFF), d3 = (int)(v31 >> 48);
            const int m0 = (int)((hc >> 12) & 1ull), m1 = (int)((hc >> 28) & 1ull);
            const int m2 = (int)((hc >> 44) & 1ull), m3 = (int)((hc >> 60) & 1ull);
            p4.x = m0 ? 1.0f : (d0 ? 0.0f : 2.0f);
            p4.y = m1 ? 1.0f : (d1 ? 0.0f : 2.0f);
            p4.z = m2 ? 1.0f : (d2 ? 0.0f : 2.0f);
            p4.w = m3 ? 1.0f : (d3 ? 0.0f : 2.0f);
        }
        *(float4*)orow = r4;
        *(float4*)prow = p4;
        orow += WW; prow += WW;

        v35 = v35 + (nA & M6) - (oA & M6);
        v31 = v31 + ((nB >> 6) & M6) - ((oB >> 6) & M6);
    }
}

// ---------------- Fallback: single-kernel tiled version (R1, passing) -------
constexpr int TX = 64;
constexpr int TY = 32;
constexpr int HALO = 17;
constexpr int IW = TX + 2 * HALO;   // 98
constexpr int IH = TY + 2 * HALO;   // 66
constexpr int SIN = IW + 1;         // 99

__global__ __launch_bounds__(256)
void label_gen_kernel(const float* __restrict__ in, float* __restrict__ out) {
    __shared__ float s_in[IH * SIN];
    __shared__ float s_v35[TY * SIN];
    __shared__ float s_v31[TY * SIN];

    const int tid = threadIdx.x;
    const int gx0 = blockIdx.x * TX;
    const int gy0 = blockIdx.y * TY;
    const int b   = blockIdx.z;
    const float* __restrict__ src = in + (size_t)b * NPIX;

    for (int idx = tid; idx < IH * IW; idx += 256) {
        int r = idx / IW;
        int c = idx - r * IW;
        int gy = gy0 - HALO + r;
        int gx = gx0 - HALO + c;
        float v = 0.0f;
        if (gy >= 0 && gy < HH && gx >= 0 && gx < WW) v = src[gy * WW + gx];
        s_in[r * SIN + c] = v;
    }
    __syncthreads();

    if (tid < 196) {
        const int seg = (tid >= 98) ? 1 : 0;
        const int c   = tid - seg * 98;
        const int y0  = seg * (TY / 2);
        float s35 = 0.0f;
        #pragma unroll
        for (int r = 0; r < 35; ++r) s35 += s_in[(y0 + r) * SIN + c];
        float s31 = s35 - s_in[(y0 + 0) * SIN + c] - s_in[(y0 + 1) * SIN + c]
                        - s_in[(y0 + 33) * SIN + c] - s_in[(y0 + 34) * SIN + c];
        s_v35[y0 * SIN + c] = s35;
        s_v31[y0 * SIN + c] = s31;
        for (int y = y0 + 1; y < y0 + TY / 2; ++y) {
            s35 += s_in[(y + 34) * SIN + c] - s_in[(y - 1) * SIN + c];
            s31 += s_in[(y + 32) * SIN + c] - s_in[(y + 1) * SIN + c];
            s_v35[y * SIN + c] = s35;
            s_v31[y * SIN + c] = s31;
        }
    }
    __syncthreads();

    const int y  = tid >> 3;
    const int x0 = (tid & 7) * 8;
    float h35 = 0.0f, h31 = 0.0f;
    #pragma unroll
    for (int c = x0; c < x0 + 35; ++c)      h35 += s_v35[y * SIN + c];
    #pragma unroll
    for (int c = x0 + 2; c <= x0 + 32; ++c) h31 += s_v31[y * SIN + c];

    float* __restrict__ out_r = out + (size_t)b * NPIX + (size_t)(gy0 + y) * WW + gx0;
    float* __restrict__ out_p = out + (size_t)BATCH * NPIX + (size_t)b * NPIX
                                    + (size_t)(gy0 + y) * WW + gx0;
    #pragma unroll
    for (int i = 0; i < 8; ++i) {
        const int x = x0 + i;
        const float mm = s_in[(y + HALO) * SIN + (x + HALO)];
        out_r[x] = h35 * (1.0f / 1225.0f);
        out_p[x] = (mm > 0.5f) ? 1.0f : ((h31 > 0.5f) ? 0.0f : 2.0f);
        if (i < 7) {
            h35 += s_v35[y * SIN + x + 35] - s_v35[y * SIN + x];
            h31 += s_v31[y * SIN + x + 33] - s_v31[y * SIN + x + 2];
        }
    }
}

extern "C" void kernel_launch(void* const* d_in, const int* in_sizes, int n_in,
                              void* d_out, int out_size, void* d_ws, size_t ws_size,
                              hipStream_t stream) {
    const float* masks = (const float*)d_in[0];
    float* out = (float*)d_out;
    const size_t need = (size_t)BATCH * NPIX * sizeof(unsigned short);  // 37.7 MB
    if (ws_size >= need) {
        unsigned short* hmap = (unsigned short*)d_ws;
        dim3 g1(HH / (4 * P1_RPW), BATCH);   // 24 x 32 = 768 blocks
        hpass1_kernel<<<g1, 256, 0, stream>>>(masks, hmap);
        dim3 g2(HH / SH, BATCH);             // 16 x 32 = 512 blocks
        vpass2_kernel<<<g2, 192, 0, stream>>>(hmap, out);
    } else {
        dim3 grid(WW / TX, HH / TY, BATCH);
        label_gen_kernel<<<grid, 256, 0, stream>>>(masks, out);
    }
}

// Round 4
// 217.568 us; speedup vs baseline: 1.5513x; 1.2342x over previous
//
#include <hip/hip_runtime.h>

// LabelGenerator: masks [32,1,768,768] f32 in {0,1}
//  out0 = 35x35 box mean (SAME, zero pad)      -> f32 [32,768,768]
//  out1 = pfm: mask?1 : (31x31 dilation?0 : 2) -> f32 values 0/1/2
// Fused single kernel, bit-packed:
//  Phase A: ballot-pack 82 mask rows (48 out + 17 halo each side) into LDS
//           as 12 u64/row (+2 zero-pad u64s).
//  Phase B: 192 threads x 4 cols; horizontal H35/H31 via funnel-shift +
//           popcount + 1-bit slides (recomputed from bits on demand);
//           vertical 35/31 box sums as SWAR 4x16-bit register accumulators
//           sliding over rows. No workspace, no intermediate round-trip.
// Dilation on a 0/1 mask == (31x31 box sum >= 1).

#define BATCH 32
#define HH 768
#define WW 768
#define NPIX (HH * WW)

constexpr int TYO  = 48;               // output rows per block
constexpr int HALO = 17;               // 35//2
constexpr int ROWS = TYO + 2 * HALO;   // 82 staged rows
constexpr int NSEG = 12;               // 768/64 u64 segments per row
constexpr int SSEG = NSEG + 2;         // +2 zero-pad segments (idx 0 and 13)

__global__ __launch_bounds__(256)
void label_gen_fused(const float* __restrict__ in, float* __restrict__ out) {
    __shared__ unsigned long long sbits[ROWS][SSEG];   // 82*14*8 = 9184 B

    const int tid  = threadIdx.x;
    const int lane = tid & 63;
    const int wv   = tid >> 6;
    const int y0   = blockIdx.x * TYO;
    const int b    = blockIdx.y;
    const float* __restrict__ src = in + (size_t)b * NPIX;

    // ---- Phase A: global f32 -> LDS bit rows (ballot pack) ----
    for (int lr = wv; lr < ROWS; lr += 4) {
        const int r = y0 - HALO + lr;
        unsigned long long bb[NSEG];
        if ((unsigned)r < (unsigned)HH) {          // wave-uniform branch
            const float* rp = src + (size_t)r * WW;
            #pragma unroll
            for (int j = 0; j < NSEG; ++j)
                bb[j] = __ballot(rp[64 * j + lane] > 0.5f);
        } else {
            #pragma unroll
            for (int j = 0; j < NSEG; ++j) bb[j] = 0ull;
        }
        if (lane == 0) {
            sbits[lr][0] = 0ull;
            #pragma unroll
            for (int j = 0; j < NSEG; ++j) sbits[lr][j + 1] = bb[j];
            sbits[lr][SSEG - 1] = 0ull;
        }
    }
    __syncthreads();

    // ---- Phase B: 192 threads, 4 consecutive cols each ----
    if (tid >= 192) return;
    const int c0 = 4 * tid;
    const int s  = c0 - HALO;          // window start col (may be negative)
    const int q  = (s >> 6) + 1;       // padded u64 index (arith shift for s<0)
    const int sh = s & 63;             // odd -> never 0

    auto win = [&](int lr) -> unsigned long long {
        const unsigned long long lo = sbits[lr][q];
        const unsigned long long hi = sbits[lr][q + 1];
        return (lo >> sh) | (hi << (64 - sh));
    };
    const unsigned long long M35 = (1ull << 35) - 1;
    const unsigned long long M31 = (1ull << 31) - 1;
    // H35 for cols c0..c0+3 packed as 2x u32 (4x16-bit fields)
    auto h35swar = [&](unsigned long long w) -> uint2 {
        const int h0 = (int)__popcll(w & M35);
        const int h1 = h0 + (int)((w >> 35) & 1) - (int)(w & 1);
        const int h2 = h1 + (int)((w >> 36) & 1) - (int)((w >> 1) & 1);
        const int h3 = h2 + (int)((w >> 37) & 1) - (int)((w >> 2) & 1);
        return make_uint2((unsigned)(h0 | (h1 << 16)), (unsigned)(h2 | (h3 << 16)));
    };
    auto h31swar = [&](unsigned long long w) -> uint2 {
        const int h0 = (int)__popcll((w >> 2) & M31);
        const int h1 = h0 + (int)((w >> 33) & 1) - (int)((w >> 2) & 1);
        const int h2 = h1 + (int)((w >> 34) & 1) - (int)((w >> 3) & 1);
        const int h3 = h2 + (int)((w >> 35) & 1) - (int)((w >> 4) & 1);
        return make_uint2((unsigned)(h0 | (h1 << 16)), (unsigned)(h2 | (h3 << 16)));
    };

    // init vertical sums at y = y0 (LDS row lr = k covers image row y0-17+k)
    uint2 v35 = make_uint2(0u, 0u), v31 = make_uint2(0u, 0u);
    #pragma unroll
    for (int k = 0; k < 35; ++k) {
        const unsigned long long w = win(k);
        const uint2 a = h35swar(w);
        v35.x += a.x; v35.y += a.y;
        if (k >= 2 && k <= 32) {
            const uint2 d = h31swar(w);
            v31.x += d.x; v31.y += d.y;
        }
    }

    const int mq = (c0 >> 6) + 1;      // 4 cols never straddle a u64 (c0%4==0)
    const int mb = c0 & 63;
    float* orow = out + (size_t)b * NPIX + (size_t)y0 * WW + c0;
    float* prow = orow + (size_t)BATCH * NPIX;

    for (int i = 0; i < TYO; ++i) {
        const int lr = i + HALO;       // LDS row of output row y0+i
        const unsigned long long mword = sbits[lr][mq];

        float4 r4, p4;
        r4.x = (float)(v35.x & 0xFFFFu) * (1.0f / 1225.0f);
        r4.y = (float)(v35.x >> 16)     * (1.0f / 1225.0f);
        r4.z = (float)(v35.y & 0xFFFFu) * (1.0f / 1225.0f);
        r4.w = (float)(v35.y >> 16)     * (1.0f / 1225.0f);
        {
            const int m0 = (int)((mword >> mb) & 1ull);
            const int m1 = (int)((mword >> (mb + 1)) & 1ull);
            const int m2 = (int)((mword >> (mb + 2)) & 1ull);
            const int m3 = (int)((mword >> (mb + 3)) & 1ull);
            p4.x = m0 ? 1.0f : ((v31.x & 0xFFFFu) ? 0.0f : 2.0f);
            p4.y = m1 ? 1.0f : ((v31.x >> 16)     ? 0.0f : 2.0f);
            p4.z = m2 ? 1.0f : ((v31.y & 0xFFFFu) ? 0.0f : 2.0f);
            p4.w = m3 ? 1.0f : ((v31.y >> 16)     ? 0.0f : 2.0f);
        }
        *(float4*)orow = r4;
        *(float4*)prow = p4;
        orow += WW; prow += WW;

        if (i < TYO - 1) {
            // slide to y+1: v35 += H35(y+18) - H35(y-17); v31 += H31(y+16) - H31(y-15)
            const uint2 e35 = h35swar(win(lr + 18));
            const uint2 l35 = h35swar(win(lr - 17));
            const uint2 e31 = h31swar(win(lr + 16));
            const uint2 l31 = h31swar(win(lr - 15));
            // per-16-bit-field: value+enter <= 1225+35 < 2^16 (no carry),
            // result >= 0 (no borrow) -> SWAR-safe
            v35.x = v35.x + e35.x - l35.x;  v35.y = v35.y + e35.y - l35.y;
            v31.x = v31.x + e31.x - l31.x;  v31.y = v31.y + e31.y - l31.y;
        }
    }
}

extern "C" void kernel_launch(void* const* d_in, const int* in_sizes, int n_in,
                              void* d_out, int out_size, void* d_ws, size_t ws_size,
                              hipStream_t stream) {
    const float* masks = (const float*)d_in[0];
    float* out = (float*)d_out;
    dim3 grid(HH / TYO, BATCH);    // 16 x 32 = 512 blocks (2 per CU)
    label_gen_fused<<<grid, 256, 0, stream>>>(masks, out);
}

// Round 5
// 213.036 us; speedup vs baseline: 1.5843x; 1.0213x over previous
//
#include <hip/hip_runtime.h>

// LabelGenerator: masks [32,1,768,768] f32 in {0,1}
//  out0 = 35x35 box mean (SAME, zero pad)      -> f32 [32,768,768]
//  out1 = pfm: mask?1 : (31x31 dilation?0 : 2) -> f32 values 0/1/2
// Fused single kernel, bit-packed. R5: 512 threads/block, 4 row-groups x
// (128 col-threads x 6 cols) sharing one LDS bit-tile -> 16 waves/CU
// (2x R4's occupancy), all threads active in phase B.
// Dilation on a 0/1 mask == (31x31 box sum >= 1).

#define BATCH 32
#define HH 768
#define WW 768
#define NPIX (HH * WW)

constexpr int TYO  = 48;               // output rows per block
constexpr int HALO = 17;               // 35//2
constexpr int ROWS = TYO + 2 * HALO;   // 82 staged rows
constexpr int NSEG = 12;               // 768/64 u64 segments per row
constexpr int SSEG = NSEG + 2;         // +2 zero-pad segments
constexpr int NT   = 512;              // threads per block (8 waves)
constexpr int NG   = 4;                // row groups
constexpr int RPG  = TYO / NG;         // 12 output rows per group
constexpr int CT   = 128;              // col-threads per group
constexpr int CPT  = 6;                // cols per thread (128*6 = 768)

struct U3 { unsigned x, y, z; };       // 6x16-bit SWAR fields

__global__ __launch_bounds__(NT)
void label_gen_fused(const float* __restrict__ in, float* __restrict__ out) {
    __shared__ unsigned long long sbits[ROWS][SSEG];   // 82*14*8 = 9184 B

    const int tid  = threadIdx.x;
    const int lane = tid & 63;
    const int wv   = tid >> 6;          // 0..7
    const int y0   = blockIdx.x * TYO;
    const int b    = blockIdx.y;
    const float* __restrict__ src = in + (size_t)b * NPIX;

    // ---- Phase A: global f32 -> LDS bit rows (ballot pack), 8 waves ----
    for (int lr = wv; lr < ROWS; lr += 8) {
        const int r = y0 - HALO + lr;
        unsigned long long bb[NSEG];
        if ((unsigned)r < (unsigned)HH) {          // wave-uniform branch
            const float* rp = src + (size_t)r * WW;
            #pragma unroll
            for (int j = 0; j < NSEG; ++j)
                bb[j] = __ballot(rp[64 * j + lane] > 0.5f);
        } else {
            #pragma unroll
            for (int j = 0; j < NSEG; ++j) bb[j] = 0ull;
        }
        if (lane == 0) {
            sbits[lr][0] = 0ull;
            #pragma unroll
            for (int j = 0; j < NSEG; ++j) sbits[lr][j + 1] = bb[j];
            sbits[lr][SSEG - 1] = 0ull;
        }
    }
    __syncthreads();

    // ---- Phase B: 4 groups x 128 col-threads x 6 cols ----
    const int g   = tid >> 7;           // 0..3
    const int ct  = tid & (CT - 1);     // 0..127
    const int c0  = CPT * ct;           // 0,6,...,762
    const int yb  = y0 + RPG * g;       // group's first output row
    const int lr0 = RPG * g;            // LDS row of image row yb-17
    const int s   = c0 - HALO;
    const int q   = (s >> 6) + 1;       // padded u64 index
    const int sh  = s & 63;             // 6ct-17 is odd -> never 0

    auto win = [&](int lr) -> unsigned long long {
        return (sbits[lr][q] >> sh) | (sbits[lr][q + 1] << (64 - sh));
    };
    const unsigned long long M35 = (1ull << 35) - 1;
    const unsigned long long M31 = (1ull << 31) - 1;
    auto bit = [](unsigned long long w, int k) -> int { return (int)((w >> k) & 1ull); };

    // H35 for cols c0..c0+5 (w bit j = mask col c0-17+j), packed 6x16-bit
    auto h35swar = [&](unsigned long long w) -> U3 {
        const int h0 = (int)__popcll(w & M35);
        const int h1 = h0 + bit(w, 35) - bit(w, 0);
        const int h2 = h1 + bit(w, 36) - bit(w, 1);
        const int h3 = h2 + bit(w, 37) - bit(w, 2);
        const int h4 = h3 + bit(w, 38) - bit(w, 3);
        const int h5 = h4 + bit(w, 39) - bit(w, 4);
        return U3{(unsigned)(h0 | (h1 << 16)), (unsigned)(h2 | (h3 << 16)),
                  (unsigned)(h4 | (h5 << 16))};
    };
    auto h31swar = [&](unsigned long long w) -> U3 {
        const int d0 = (int)__popcll((w >> 2) & M31);
        const int d1 = d0 + bit(w, 33) - bit(w, 2);
        const int d2 = d1 + bit(w, 34) - bit(w, 3);
        const int d3 = d2 + bit(w, 35) - bit(w, 4);
        const int d4 = d3 + bit(w, 36) - bit(w, 5);
        const int d5 = d4 + bit(w, 37) - bit(w, 6);
        return U3{(unsigned)(d0 | (d1 << 16)), (unsigned)(d2 | (d3 << 16)),
                  (unsigned)(d4 | (d5 << 16))};
    };

    // init vertical sums at y = yb (LDS rows lr0 .. lr0+34)
    U3 v35{0, 0, 0}, v31{0, 0, 0};
    #pragma unroll
    for (int k = 0; k < 35; ++k) {
        const unsigned long long w = win(lr0 + k);
        const U3 a = h35swar(w);
        v35.x += a.x; v35.y += a.y; v35.z += a.z;
        if (k >= 2 && k <= 32) {
            const U3 d = h31swar(w);
            v31.x += d.x; v31.y += d.y; v31.z += d.z;
        }
    }

    float* orow = out + (size_t)b * NPIX + (size_t)yb * WW + c0;
    float* prow = orow + (size_t)BATCH * NPIX;

    for (int i = 0; i < RPG; ++i) {
        const int lr = lr0 + HALO + i;          // LDS row of output row yb+i
        const unsigned long long mwin = win(lr); // mask col c0+k = bit 17+k

        // rsm
        const float2 r01 = make_float2((float)(v35.x & 0xFFFFu) * (1.0f / 1225.0f),
                                       (float)(v35.x >> 16)     * (1.0f / 1225.0f));
        const float2 r23 = make_float2((float)(v35.y & 0xFFFFu) * (1.0f / 1225.0f),
                                       (float)(v35.y >> 16)     * (1.0f / 1225.0f));
        const float2 r45 = make_float2((float)(v35.z & 0xFFFFu) * (1.0f / 1225.0f),
                                       (float)(v35.z >> 16)     * (1.0f / 1225.0f));
        // pfm
        auto pv = [&](int k, unsigned dfield) -> float {
            return bit(mwin, 17 + k) ? 1.0f : (dfield ? 0.0f : 2.0f);
        };
        const float2 p01 = make_float2(pv(0, v31.x & 0xFFFFu), pv(1, v31.x >> 16));
        const float2 p23 = make_float2(pv(2, v31.y & 0xFFFFu), pv(3, v31.y >> 16));
        const float2 p45 = make_float2(pv(4, v31.z & 0xFFFFu), pv(5, v31.z >> 16));

        *(float2*)(orow + 0) = r01;
        *(float2*)(orow + 2) = r23;
        *(float2*)(orow + 4) = r45;
        *(float2*)(prow + 0) = p01;
        *(float2*)(prow + 2) = p23;
        *(float2*)(prow + 4) = p45;
        orow += WW; prow += WW;

        if (i < RPG - 1) {
            // slide: v35 += H35(y+18) - H35(y-17); v31 += H31(y+16) - H31(y-15)
            const U3 e35 = h35swar(win(lr + 18));
            const U3 l35 = h35swar(win(lr - 17));
            const U3 e31 = h31swar(win(lr + 16));
            const U3 l31 = h31swar(win(lr - 15));
            // per-field: 0 <= value <= 1225+35 < 2^16 -> SWAR-safe
            v35.x = v35.x + e35.x - l35.x;
            v35.y = v35.y + e35.y - l35.y;
            v35.z = v35.z + e35.z - l35.z;
            v31.x = v31.x + e31.x - l31.x;
            v31.y = v31.y + e31.y - l31.y;
            v31.z = v31.z + e31.z - l31.z;
        }
    }
}

extern "C" void kernel_launch(void* const* d_in, const int* in_sizes, int n_in,
                              void* d_out, int out_size, void* d_ws, size_t ws_size,
                              hipStream_t stream) {
    const float* masks = (const float*)d_in[0];
    float* out = (float*)d_out;
    dim3 grid(HH / TYO, BATCH);    // 16 x 32 = 512 blocks, 2 per CU
    label_gen_fused<<<grid, NT, 0, stream>>>(masks, out);
}